// Round 1
// baseline (85.554 us; speedup 1.0000x reference)
//
#include <hip/hip_runtime.h>

typedef __attribute__((ext_vector_type(8))) short short8;
typedef __attribute__((ext_vector_type(4))) float f32x4;
typedef unsigned short ushort_t;

constexpr int N = 16384;
constexpr int K = 1024;
constexpr int M = 1024;

__device__ inline ushort_t f32_to_bf16(float f) {
    unsigned u = __builtin_bit_cast(unsigned, f);
    unsigned r = (u + 0x7fffu + ((u >> 16) & 1u)) >> 16;
    return (ushort_t)r;
}

__device__ inline void gload_lds16(const ushort_t* g, ushort_t* l) {
    __builtin_amdgcn_global_load_lds(
        (const __attribute__((address_space(1))) unsigned int*)g,
        (__attribute__((address_space(3))) unsigned int*)l,
        16, 0, 0);
}

// One block per mu row: norm, W = mu_n*inv_std (bf16), mmh = -0.5*sum(mu_n^2*inv_std)
__global__ void prep_mu(const float* __restrict__ mu, const float* __restrict__ stdv,
                        ushort_t* __restrict__ Wb, float* __restrict__ mmh) {
    int m = blockIdx.x;
    int t = threadIdx.x;
    float4 v = ((const float4*)(mu + (size_t)m * K))[t];
    float4 s = ((const float4*)stdv)[t];
    float ix = 1.0f / s.x, iy = 1.0f / s.y, iz = 1.0f / s.z, iw = 1.0f / s.w;
    float sum2  = v.x * v.x + v.y * v.y + v.z * v.z + v.w * v.w;
    float sum2w = v.x * v.x * ix + v.y * v.y * iy + v.z * v.z * iz + v.w * v.w * iw;
    for (int off = 32; off > 0; off >>= 1) {
        sum2  += __shfl_down(sum2, off, 64);
        sum2w += __shfl_down(sum2w, off, 64);
    }
    __shared__ float r2[4], r2w[4];
    __shared__ float s_scale;
    int lane = t & 63, w = t >> 6;
    if (lane == 0) { r2[w] = sum2; r2w[w] = sum2w; }
    __syncthreads();
    if (t == 0) {
        float tot2  = r2[0] + r2[1] + r2[2] + r2[3];
        float tot2w = r2w[0] + r2w[1] + r2w[2] + r2w[3];
        mmh[m] = -0.5f * tot2w / tot2;
        s_scale = rsqrtf(tot2);
    }
    __syncthreads();
    float sc = s_scale;
    ushort_t* wout = Wb + (size_t)m * K + t * 4;
    ushort_t o0 = f32_to_bf16(v.x * ix * sc);
    ushort_t o1 = f32_to_bf16(v.y * iy * sc);
    ushort_t o2 = f32_to_bf16(v.z * iz * sc);
    ushort_t o3 = f32_to_bf16(v.w * iw * sc);
    // 8-byte vector store
    ushort_t tmp[4] = {o0, o1, o2, o3};
    *(uint2*)wout = *(const uint2*)tmp;
}

// One block per x row: x->bf16, xxh = -0.5*sum(x^2*inv_std)
__global__ void prep_x(const float* __restrict__ x, const float* __restrict__ stdv,
                       ushort_t* __restrict__ xb, float* __restrict__ xxh) {
    int n = blockIdx.x;
    int t = threadIdx.x;
    float4 v = ((const float4*)(x + (size_t)n * K))[t];
    float4 s = ((const float4*)stdv)[t];
    float ssum = v.x * v.x / s.x + v.y * v.y / s.y + v.z * v.z / s.z + v.w * v.w / s.w;
    ushort_t o0 = f32_to_bf16(v.x);
    ushort_t o1 = f32_to_bf16(v.y);
    ushort_t o2 = f32_to_bf16(v.z);
    ushort_t o3 = f32_to_bf16(v.w);
    ushort_t tmp[4] = {o0, o1, o2, o3};
    *(uint2*)(xb + (size_t)n * K + t * 4) = *(const uint2*)tmp;
    for (int off = 32; off > 0; off >>= 1) ssum += __shfl_down(ssum, off, 64);
    __shared__ float red[4];
    if ((t & 63) == 0) red[t >> 6] = ssum;
    __syncthreads();
    if (t == 0) xxh[n] = -0.5f * (red[0] + red[1] + red[2] + red[3]);
}

// 128x128 tile bf16 GEMM (C = A * B^T), epilogue adds xxh[row] + mmh[col].
// A: [N][K] bf16 row-major, B: [M][K] bf16 row-major.
#define BK 32
__global__ __launch_bounds__(256) void gemm_ep(
    const ushort_t* __restrict__ A, const ushort_t* __restrict__ B,
    const float* __restrict__ xxh, const float* __restrict__ mmh,
    float* __restrict__ C) {
    __shared__ ushort_t Als[128 * BK];
    __shared__ ushort_t Bls[128 * BK];
    int t = threadIdx.x;
    int lane = t & 63;
    int wave = t >> 6;
    int wr = wave >> 1, wc = wave & 1;
    int bid = blockIdx.x;
    int tm = bid & 7;      // M/128 = 8
    int tn = bid >> 3;     // N/128 = 128
    const ushort_t* Abase = A + (size_t)tn * 128 * K;
    const ushort_t* Bbase = B + (size_t)tm * 128 * K;

    f32x4 acc[4][4] = {};

    int lrow = lane & 15;
    int lk = lane >> 4;
    int i0 = t;        // staging chunk ids (16B chunks)
    int i1 = 256 + t;
    ushort_t* la0 = Als + (size_t)(t & 0xC0) * 8;
    ushort_t* la1 = Als + 2048 + (size_t)(t & 0xC0) * 8;
    ushort_t* lb0 = Bls + (size_t)(t & 0xC0) * 8;
    ushort_t* lb1 = Bls + 2048 + (size_t)(t & 0xC0) * 8;

    for (int k0 = 0; k0 < K; k0 += BK) {
        gload_lds16(Abase + (size_t)(i0 >> 2) * K + k0 + (i0 & 3) * 8, la0);
        gload_lds16(Abase + (size_t)(i1 >> 2) * K + k0 + (i1 & 3) * 8, la1);
        gload_lds16(Bbase + (size_t)(i0 >> 2) * K + k0 + (i0 & 3) * 8, lb0);
        gload_lds16(Bbase + (size_t)(i1 >> 2) * K + k0 + (i1 & 3) * 8, lb1);
        __syncthreads();
        short8 af[4], bfr[4];
#pragma unroll
        for (int mi = 0; mi < 4; ++mi)
            af[mi] = *(const short8*)&Als[(wr * 64 + mi * 16 + lrow) * BK + lk * 8];
#pragma unroll
        for (int ni = 0; ni < 4; ++ni)
            bfr[ni] = *(const short8*)&Bls[(wc * 64 + ni * 16 + lrow) * BK + lk * 8];
#pragma unroll
        for (int mi = 0; mi < 4; ++mi)
#pragma unroll
            for (int ni = 0; ni < 4; ++ni)
                acc[mi][ni] = __builtin_amdgcn_mfma_f32_16x16x32_bf16(
                    af[mi], bfr[ni], acc[mi][ni], 0, 0, 0);
        __syncthreads();
    }

    int rowb = tn * 128 + wr * 64;
    int colb = tm * 128 + wc * 64;
#pragma unroll
    for (int mi = 0; mi < 4; ++mi) {
#pragma unroll
        for (int ni = 0; ni < 4; ++ni) {
            int col = colb + ni * 16 + lrow;
            float mh = mmh[col];
#pragma unroll
            for (int j = 0; j < 4; ++j) {
                int row = rowb + mi * 16 + lk * 4 + j;
                C[(size_t)row * M + col] = acc[mi][ni][j] + xxh[row] + mh;
            }
        }
    }
}

extern "C" void kernel_launch(void* const* d_in, const int* in_sizes, int n_in,
                              void* d_out, int out_size, void* d_ws, size_t ws_size,
                              hipStream_t stream) {
    const float* x    = (const float*)d_in[0];
    const float* mu   = (const float*)d_in[1];
    const float* stdv = (const float*)d_in[2];
    float* out = (float*)d_out;

    char* ws = (char*)d_ws;
    ushort_t* xb  = (ushort_t*)ws;                                  // N*K*2 = 32 MB
    ushort_t* Wb  = (ushort_t*)(ws + (size_t)N * K * 2);            // M*K*2 = 2 MB
    float*    xxh = (float*)(ws + (size_t)N * K * 2 + (size_t)M * K * 2);
    float*    mmh = (float*)((char*)xxh + (size_t)N * sizeof(float));

    prep_mu<<<M, 256, 0, stream>>>(mu, stdv, Wb, mmh);
    prep_x<<<N, 256, 0, stream>>>(x, stdv, xb, xxh);
    gemm_ep<<<(N / 128) * (M / 128), 256, 0, stream>>>(xb, Wb, xxh, mmh, out);
}

// Round 3
// 73.427 us; speedup vs baseline: 1.1652x; 1.1652x over previous
//
#include <hip/hip_runtime.h>

typedef __attribute__((ext_vector_type(8))) short short8;
typedef __attribute__((ext_vector_type(4))) float f32x4;
typedef unsigned short ushort_t;

constexpr int N = 16384;
constexpr int K = 1024;
constexpr int M = 1024;

#define WAITVM(n) asm volatile("s_waitcnt vmcnt(" #n ")" ::: "memory")

__device__ inline ushort_t f32_to_bf16(float f) {
    unsigned u = __builtin_bit_cast(unsigned, f);
    unsigned r = (u + 0x7fffu + ((u >> 16) & 1u)) >> 16;
    return (ushort_t)r;
}

__device__ inline void gload_lds16(const ushort_t* g, ushort_t* l) {
    __builtin_amdgcn_global_load_lds(
        (const __attribute__((address_space(1))) unsigned int*)g,
        (__attribute__((address_space(3))) unsigned int*)l,
        16, 0, 0);
}

// One block per mu row: norm, W = mu_n*inv_std (bf16), mmh = -0.5*sum(mu_n^2*inv_std)
__global__ void prep_mu(const float* __restrict__ mu, const float* __restrict__ stdv,
                        ushort_t* __restrict__ Wb, float* __restrict__ mmh) {
    int m = blockIdx.x;
    int t = threadIdx.x;
    float4 v = ((const float4*)(mu + (size_t)m * K))[t];
    float4 s = ((const float4*)stdv)[t];
    float ix = 1.0f / s.x, iy = 1.0f / s.y, iz = 1.0f / s.z, iw = 1.0f / s.w;
    float sum2  = v.x * v.x + v.y * v.y + v.z * v.z + v.w * v.w;
    float sum2w = v.x * v.x * ix + v.y * v.y * iy + v.z * v.z * iz + v.w * v.w * iw;
    for (int off = 32; off > 0; off >>= 1) {
        sum2  += __shfl_down(sum2, off, 64);
        sum2w += __shfl_down(sum2w, off, 64);
    }
    __shared__ float r2[4], r2w[4];
    __shared__ float s_scale;
    int lane = t & 63, w = t >> 6;
    if (lane == 0) { r2[w] = sum2; r2w[w] = sum2w; }
    __syncthreads();
    if (t == 0) {
        float tot2  = r2[0] + r2[1] + r2[2] + r2[3];
        float tot2w = r2w[0] + r2w[1] + r2w[2] + r2w[3];
        mmh[m] = -0.5f * tot2w / tot2;
        s_scale = rsqrtf(tot2);
    }
    __syncthreads();
    float sc = s_scale;
    ushort_t* wout = Wb + (size_t)m * K + t * 4;
    ushort_t tmp[4] = {f32_to_bf16(v.x * ix * sc), f32_to_bf16(v.y * iy * sc),
                       f32_to_bf16(v.z * iz * sc), f32_to_bf16(v.w * iw * sc)};
    *(uint2*)wout = *(const uint2*)tmp;
}

// Wave-per-row: x->bf16, xxh = -0.5*sum(x^2*inv_std). No barriers, no LDS.
__global__ __launch_bounds__(256) void prep_x(const float* __restrict__ x,
                                              const float* __restrict__ stdv,
                                              ushort_t* __restrict__ xb,
                                              float* __restrict__ xxh) {
    int row = blockIdx.x * 4 + (threadIdx.x >> 6);
    int lane = threadIdx.x & 63;
    const float4* src = (const float4*)(x + (size_t)row * K);
    const float4* sp  = (const float4*)stdv;
    uint2* dst = (uint2*)(xb + (size_t)row * K);
    float ssum = 0.f;
#pragma unroll
    for (int i = 0; i < 4; ++i) {
        int idx = lane + 64 * i;
        float4 v = src[idx];
        float4 s = sp[idx];
        ssum += v.x * v.x / s.x + v.y * v.y / s.y + v.z * v.z / s.z + v.w * v.w / s.w;
        ushort_t tmp[4] = {f32_to_bf16(v.x), f32_to_bf16(v.y),
                           f32_to_bf16(v.z), f32_to_bf16(v.w)};
        dst[idx] = *(const uint2*)tmp;
    }
#pragma unroll
    for (int off = 32; off > 0; off >>= 1) ssum += __shfl_down(ssum, off, 64);
    if (lane == 0) xxh[row] = -0.5f * ssum;
}

// ---------------------------------------------------------------------------
// 256x256 tile, BK=64, 8 waves (2Mx4N), double-buffered LDS (128 KiB),
// counted-vmcnt pipeline (T4), XOR-swizzled LDS via pre-swizzled global
// source (T2, rule 21), XCD-aware block swizzle (T1).
// C = A * B^T + xxh[row] + mmh[col];  A:[N][K] bf16, B(=W):[M][K] bf16.
// ---------------------------------------------------------------------------
#define BK 64
#define TILE_ELEMS (256 * BK)          // 16384 ushorts = 32 KiB per buffer

__global__ __launch_bounds__(512, 2) void gemm_ep(
    const ushort_t* __restrict__ A, const ushort_t* __restrict__ B,
    const float* __restrict__ xxh, const float* __restrict__ mmh,
    float* __restrict__ C) {
    __shared__ ushort_t Als[2 * TILE_ELEMS];   // 64 KiB
    __shared__ ushort_t Bls[2 * TILE_ELEMS];   // 64 KiB

    int t = threadIdx.x;
    int lane = t & 63;
    int wave = t >> 6;
    int wr = wave >> 2;          // 0..1 (M half)
    int wc = wave & 3;           // 0..3 (N quarter)
    int r  = lane & 15;
    int lk = lane >> 4;

    // T1: XCD swizzle. nwg=256 = 8 XCDs x 32.
    int bid = blockIdx.x;
    int s = (bid & 7) * 32 + (bid >> 3);
    int tm = s >> 6;             // 0..3   (M/256)
    int tn = s & 63;             // 0..63  (N/256)

    const ushort_t* Abase = A + (size_t)tn * 256 * K;
    const ushort_t* Bbase = B + (size_t)tm * 256 * K;

    f32x4 acc[8][4] = {};

    // staging: 2048 16B-chunks per matrix per K-tile; 4 per thread.
    // chunk c: lds row = c>>3, lds slot = c&7; global slot = (c&7) ^ (row&7)
    // (inverse swizzle on SOURCE; LDS dest linear for global_load_lds — rule 21)
    // NOTE: macro locals use trailing underscore — no shadowing of loop vars!
#define STAGE(kt_, buf_)                                                        \
    {                                                                           \
        const ushort_t* Ag_ = Abase + (size_t)(kt_) * BK;                       \
        const ushort_t* Bg_ = Bbase + (size_t)(kt_) * BK;                       \
        ushort_t* Al_ = Als + (buf_) * TILE_ELEMS;                              \
        ushort_t* Bl_ = Bls + (buf_) * TILE_ELEMS;                              \
        _Pragma("unroll")                                                       \
        for (int i_ = 0; i_ < 4; ++i_) {                                        \
            int c_ = i_ * 512 + t;                                              \
            int row_ = c_ >> 3;                                                 \
            int slot_ = (c_ & 7) ^ (row_ & 7);                                  \
            gload_lds16(Ag_ + (size_t)row_ * K + slot_ * 8,                     \
                        Al_ + (i_ * 512 + (wave << 6)) * 8);                    \
        }                                                                       \
        _Pragma("unroll")                                                       \
        for (int i_ = 0; i_ < 4; ++i_) {                                        \
            int c_ = i_ * 512 + t;                                              \
            int row_ = c_ >> 3;                                                 \
            int slot_ = (c_ & 7) ^ (row_ & 7);                                  \
            gload_lds16(Bg_ + (size_t)row_ * K + slot_ * 8,                     \
                        Bl_ + (i_ * 512 + (wave << 6)) * 8);                    \
        }                                                                       \
    }

    // prologue: fill both buffers, wait for buffer 0 only
    STAGE(0, 0);                      // 8 loads
    STAGE(1, 1);                      // 8 loads (16 outstanding)
    WAITVM(8);                        // kt=0 landed
    __builtin_amdgcn_s_barrier();

    int cur = 0;
    const int NT = K / BK;            // 16 K-tiles
    for (int kt = 0; kt < NT; ++kt) {
        const ushort_t* As = Als + cur * TILE_ELEMS;
        const ushort_t* Bs = Bls + cur * TILE_ELEMS;
        // swizzled ds_read: element off = row*64 + ((lk ^ (r&7) ^ (ks<<2))*8)
#pragma unroll
        for (int ks = 0; ks < 2; ++ks) {
            short8 af[8], bfr[4];
#pragma unroll
            for (int mi = 0; mi < 8; ++mi)
                af[mi] = *(const short8*)&As[((wr * 128 + mi * 16 + r) << 6) +
                                             ((lk ^ (r & 7) ^ (ks << 2)) << 3)];
#pragma unroll
            for (int ni = 0; ni < 4; ++ni)
                bfr[ni] = *(const short8*)&Bs[((wc * 64 + ni * 16 + r) << 6) +
                                              ((lk ^ (r & 7) ^ (ks << 2)) << 3)];
#pragma unroll
            for (int mi = 0; mi < 8; ++mi)
#pragma unroll
                for (int ni = 0; ni < 4; ++ni)
                    acc[mi][ni] = __builtin_amdgcn_mfma_f32_16x16x32_bf16(
                        af[mi], bfr[ni], acc[mi][ni], 0, 0, 0);
        }
        if (kt == NT - 1) break;
        __builtin_amdgcn_s_barrier();           // all waves done reading buf[cur]
        if (kt < NT - 2) {
            STAGE(kt + 2, cur);                 // overwrite consumed buffer
            WAITVM(8);                          // kt+1 landed; kt+2 stays in flight
        } else {
            WAITVM(0);                          // drain last tile (kt+1 = NT-1)
        }
        __builtin_amdgcn_s_barrier();           // buf[cur^1] ready for all waves
        cur ^= 1;
    }

    // epilogue: C[row][col] = acc + xxh[row] + mmh[col]
    int rowb = tn * 256 + wr * 128;
    int colb = tm * 256 + wc * 64;
#pragma unroll
    for (int mi = 0; mi < 8; ++mi) {
        float xh[4];
#pragma unroll
        for (int j = 0; j < 4; ++j) xh[j] = xxh[rowb + mi * 16 + lk * 4 + j];
#pragma unroll
        for (int ni = 0; ni < 4; ++ni) {
            int col = colb + ni * 16 + r;
            float mh = mmh[col];
#pragma unroll
            for (int j = 0; j < 4; ++j) {
                int row = rowb + mi * 16 + lk * 4 + j;
                C[(size_t)row * M + col] = acc[mi][ni][j] + xh[j] + mh;
            }
        }
    }
#undef STAGE
}

extern "C" void kernel_launch(void* const* d_in, const int* in_sizes, int n_in,
                              void* d_out, int out_size, void* d_ws, size_t ws_size,
                              hipStream_t stream) {
    const float* x    = (const float*)d_in[0];
    const float* mu   = (const float*)d_in[1];
    const float* stdv = (const float*)d_in[2];
    float* out = (float*)d_out;

    char* ws = (char*)d_ws;
    ushort_t* xb  = (ushort_t*)ws;                                  // N*K*2 = 32 MB
    ushort_t* Wb  = (ushort_t*)(ws + (size_t)N * K * 2);            // M*K*2 = 2 MB
    float*    xxh = (float*)(ws + (size_t)N * K * 2 + (size_t)M * K * 2);
    float*    mmh = (float*)((char*)xxh + (size_t)N * sizeof(float));

    prep_mu<<<M, 256, 0, stream>>>(mu, stdv, Wb, mmh);
    prep_x<<<N / 4, 256, 0, stream>>>(x, stdv, xb, xxh);
    gemm_ep<<<(N / 256) * (M / 256), 512, 0, stream>>>(xb, Wb, xxh, mmh, out);
}